// Round 4
// baseline (2498.914 us; speedup 1.0000x reference)
//
#include <hip/hip_runtime.h>
#include <hip/hip_bf16.h>

#define DEV __device__ __forceinline__

typedef __bf16 bf16x8 __attribute__((ext_vector_type(8)));
typedef float  f32x4  __attribute__((ext_vector_type(4)));
typedef unsigned short u16;

DEV u16   f2b(float f) { __bf16 h = (__bf16)f; return __builtin_bit_cast(u16, h); }
DEV float b2f(u16 x)   { return __builtin_bit_cast(float, ((unsigned)x) << 16); }

DEV void gl_lds16(const u16* g, u16* l) {
  __builtin_amdgcn_global_load_lds((const __attribute__((address_space(1))) void*)g,
                                   (__attribute__((address_space(3))) void*)l, 16, 0, 0);
}

// Grid barrier, hardened for per-XCD L2 non-coherence:
//  - __syncthreads(): all threads' stores drained (vmcnt0) -> resident in own L2
//  - thread 0: SYSTEM-scope release fence (L2 writeback) -> arrive -> spin
//    (system-scope atomic, coherent at L3) -> SYSTEM-scope acquire fence
//    (L1/L2 invalidate) -> __syncthreads() releases the WG.
// Monotonic counter, zeroed by k_init every launch => graph-replay-safe.
DEV void gridbar(unsigned* bar, unsigned& gen) {
  __syncthreads();
  if (threadIdx.x == 0) {
    __builtin_amdgcn_fence(__ATOMIC_RELEASE, "");       // system: wb L2
    gen += 256u;                                        // NWG
    __hip_atomic_fetch_add(bar, 1u, __ATOMIC_RELAXED, __HIP_MEMORY_SCOPE_SYSTEM);
    while (__hip_atomic_load(bar, __ATOMIC_RELAXED, __HIP_MEMORY_SCOPE_SYSTEM) < gen)
      __builtin_amdgcn_s_sleep(4);
    __builtin_amdgcn_fence(__ATOMIC_ACQUIRE, "");       // system: inv L1/L2
  }
  __syncthreads();
}

// ---------------------------------------------------------------------------
// 64x32-tile GEMM step, BK=128 double-buffered (R2's proven pipeline).
// D[m,e] = sum_d A[m,d]*B[e,d];  LDS: A 2x16KB rows 64x256B, B 2x8KB rows 32x256B,
// swizzle byte ^= (row&7)<<4 on pre-swizzled global source + ds_read.
// MODE 0: += pre[t(c-1)], write bf16 (+fp32 outf);  MODE 1: phase3 + silu epilogue
// MODE 2: squaring (D and D^T);                     MODE 3: += bias, write bf16
// ---------------------------------------------------------------------------
template<int MODE>
DEV void gemm_tile(u16* sm, const u16* A, const u16* B,
                   int m0, int e0, const u16* preb,
                   const float* bias, u16* outb,
                   u16* outbT, float* outf,
                   float* out0, int c)
{
  const int K = 1024;
  int tid = threadIdx.x, lane = tid & 63, w = tid >> 6;
  int wrow = (w >> 1) << 5, wcol = (w & 1) << 4;
  u16* As = sm;            // [2][8192] u16
  u16* Bs = sm + 16384;    // [2][4096] u16

  f32x4 acc[2] = {};

  int rA[4], cA[4], rB[2], cB[2];
#pragma unroll
  for (int j = 0; j < 4; ++j) {
    int p = (j * 4 + w) * 1024 + lane * 16;
    int r = p >> 8, o = (p & 255) ^ ((r & 7) << 4);
    rA[j] = r; cA[j] = o >> 1;
  }
#pragma unroll
  for (int j = 0; j < 2; ++j) {
    int p = (j * 4 + w) * 1024 + lane * 16;
    int r = p >> 8, o = (p & 255) ^ ((r & 7) << 4);
    rB[j] = r; cB[j] = o >> 1;
  }
  auto stage = [&](int buf, int kt) {
#pragma unroll
    for (int j = 0; j < 4; ++j)
      gl_lds16(A + (m0 + rA[j]) * K + kt + cA[j], As + buf * 8192 + (j * 4 + w) * 512);
#pragma unroll
    for (int j = 0; j < 2; ++j)
      gl_lds16(B + (e0 + rB[j]) * K + kt + cB[j], Bs + buf * 4096 + (j * 4 + w) * 512);
  };

  stage(0, 0);
  asm volatile("s_waitcnt vmcnt(0)" ::: "memory");
  __syncthreads();

  int buf = 0;
  for (int kt = 0; kt < K; kt += 128, buf ^= 1) {
    if (kt + 128 < K) stage(buf ^ 1, kt + 128);
#pragma unroll
    for (int ks = 0; ks < 4; ++ks) {
      int oa = ks * 64 + ((lane >> 4) << 4);
      int ra0 = wrow + (lane & 15), ra1 = ra0 + 16;
      int rb  = wcol + (lane & 15);
      bf16x8 af0 = *(const bf16x8*)((const char*)(As + buf * 8192) + ra0 * 256 + (oa ^ ((ra0 & 7) << 4)));
      bf16x8 af1 = *(const bf16x8*)((const char*)(As + buf * 8192) + ra1 * 256 + (oa ^ ((ra1 & 7) << 4)));
      bf16x8 bfv = *(const bf16x8*)((const char*)(Bs + buf * 4096) + rb * 256 + (oa ^ ((rb & 7) << 4)));
      acc[0] = __builtin_amdgcn_mfma_f32_16x16x32_bf16(af0, bfv, acc[0], 0, 0, 0);
      acc[1] = __builtin_amdgcn_mfma_f32_16x16x32_bf16(af1, bfv, acc[1], 0, 0, 0);
    }
    asm volatile("s_waitcnt vmcnt(0)" ::: "memory");
    __syncthreads();
  }

  int l4 = ((lane >> 4) << 2), lc = lane & 15;
#pragma unroll
  for (int s = 0; s < 2; ++s)
#pragma unroll
    for (int j = 0; j < 4; ++j) {
      int row = m0 + wrow + s * 16 + l4 + j;   // C/D: row=(lane>>4)*4+reg
      int col = e0 + wcol + lc;                // C/D: col=lane&15
      float v = acc[s][j];
      if (MODE == 0) {
        int pt = ((row >> 3) << 5) + c - 1;
        v += b2f(preb[(pt * 8 + (row & 7)) * 1024 + col]);
        outb[row * 1024 + col] = f2b(v);
        if (outf) outf[row * 1024 + col] = v;
      } else if (MODE == 1) {
        int pt = ((row >> 3) << 5) + c - 1;
        v += b2f(preb[(pt * 8 + (row & 7)) * 1024 + col]);
        outb[row * 1024 + col] = f2b(v);
        int t = pt + 1;
        outf[t * 8192 + (row & 7) * 1024 + col] = v;            // h_all[t]
        float sg = 1.f / (1.f + __expf(-v));
        out0[(t - 1) * 8192 + (row & 7) * 1024 + col] = v * v * sg;
      } else if (MODE == 2) {
        u16 h = f2b(v);
        outb[row * 1024 + col] = h;
        if (outbT) outbT[col * 1024 + row] = h;
      } else {
        v += bias[col];
        outb[row * 1024 + col] = f2b(v);
      }
    }
}

// matvec unit: hout[r,e] = sum_d W[e,d]*hin[r,d] + addv[map(r),e]
DEV void matvec_unit(int tid, int e16, int rblk, const float* hin,
                     const u16* W, const float* addv,
                     float* hout, u16* houtb,
                     int acoff, int bcoff, bool nr64)
{
  int lg = tid & 15;
  int e = e16 * 16 + (tid >> 4);
  int r0 = rblk * 8;
  float acc[8] = {0,0,0,0,0,0,0,0};
  const u16* wrow = W + e * 1024;
#pragma unroll
  for (int i = 0; i < 8; ++i) {
    int d0 = lg * 8 + i * 128;
    ushort4 w0 = *(const ushort4*)(wrow + d0);
    ushort4 w1 = *(const ushort4*)(wrow + d0 + 4);
    float wa = b2f(w0.x), wb = b2f(w0.y), wc = b2f(w0.z), wd = b2f(w0.w);
    float we_ = b2f(w1.x), wf = b2f(w1.y), wg = b2f(w1.z), wh = b2f(w1.w);
#pragma unroll
    for (int b = 0; b < 8; ++b) {
      const float* hr = hin + (r0 + b) * 1024 + d0;
      float4 h0v = *(const float4*)hr;
      float4 h1v = *(const float4*)(hr + 4);
      acc[b] += wa*h0v.x + wb*h0v.y + wc*h0v.z + wd*h0v.w
              + we_*h1v.x + wf*h1v.y + wg*h1v.z + wh*h1v.w;
    }
  }
#pragma unroll
  for (int m = 1; m < 16; m <<= 1)
#pragma unroll
    for (int b = 0; b < 8; ++b) acc[b] += __shfl_xor(acc[b], m);
  if (lg == 0) {
#pragma unroll
    for (int b = 0; b < 8; ++b) {
      int r = r0 + b;
      int ai = nr64 ? (((r >> 3) << 6) + (acoff << 3) + (r & 7)) : r;
      float v = acc[b] + addv[ai * 1024 + e];
      hout[r * 1024 + e] = v;
      if (houtb) {
        int bi = nr64 ? (((r >> 3) << 6) + (bcoff << 3) + (r & 7)) : r;
        houtb[bi * 1024 + e] = f2b(v);
      }
    }
  }
}

// ---------------------------------------------------------------------------
// Persistent cooperative kernel: pre-GEMM, squarings, phase1, phase2, phase3.
// 256 WGs x 256 threads, hardened grid barriers between dependent steps.
// xb (x as bf16) and hall are derived from out0 (same buffer family; no
// __restrict__ aliasing UB).
// ---------------------------------------------------------------------------
__global__ __launch_bounds__(256) void persist(char* __restrict__ ws,
                                               const float* __restrict__ bias,
                                               float* out0)
{
  u16*   pre_b = (u16*)(ws);
  u16*   wh_b  = (u16*)(ws + 33554432);
  u16*   whT_b = (u16*)(ws + 35651584);
  u16*   sA    = (u16*)(ws + 37748736);
  u16*   sAT   = (u16*)(ws + 39845888);
  u16*   sB    = (u16*)(ws + 41943040);
  u16*   sBT   = (u16*)(ws + 44040192);
  float* lC    = (float*)(ws + 46137344);
  u16*   lCT   = (u16*)(ws + 46137344);
  u16*   lb0   = (u16*)(ws + 48234496);
  u16*   lb1   = (u16*)(ws + 49283072);
  u16*   wxb   = (u16*)(ws + 48234496);   // aliases lb0/lb1 (dead until linit)
  u16*   bnd_b = (u16*)(ws + 50331648);
  float* lam0  = (float*)(ws + 51380224);
  float* lam1  = (float*)(ws + 51642368);
  float* bndS  = (float*)(ws + 51904512);
  float* pc0   = (float*)(ws + 52166656);
  float* pc1   = (float*)(ws + 52428800);
  unsigned* bar = (unsigned*)(ws + 52711424);

  float* hall = out0 + 16777216;
  u16*   xb   = (u16*)out0;               // x bf16 staged in out0 region

  __shared__ u16 sm[24576];   // 48KB: A dbuf 32KB + B dbuf 16KB
  int g = blockIdx.x, tid = threadIdx.x;
  unsigned gen = 0;

  // ---- step 0: pre = x @ Wx^T + b  (8192 tiles, 32 per WG) ----
  for (int i = 0; i < 32; ++i) {
    int t = i * 256 + g;
    gemm_tile<3>(sm, xb, wxb, (t >> 5) * 64, (t & 31) * 32, nullptr, bias,
                 pre_b, nullptr, nullptr, nullptr, 0);
  }
  gridbar(bar, gen);

  // ---- step 1: Wh powers by squaring (8 steps, 512 tiles each => 2/WG) ----
  const u16* qa[8]  = {wh_b,  sA,  sB,  sA,  sB,  sA,  sB,    whT_b};
  const u16* qat[8] = {whT_b, sAT, sBT, sAT, sBT, sAT, sBT,   lCT};
  u16*       qo[8]  = {sA,    sB,  sA,  sB,  sA,  sB,  whT_b, sB};
  u16*       qot[8] = {sAT,   sBT, sAT, sBT, sAT, sBT, lCT,   nullptr};
#pragma unroll
  for (int sq = 0; sq < 8; ++sq) {
    for (int i = 0; i < 2; ++i) {
      int t = i * 256 + g;
      gemm_tile<2>(sm, qa[sq], qat[sq], (t >> 5) * 64, (t & 31) * 32, nullptr,
                   nullptr, qo[sq], qot[sq], nullptr, nullptr, 0);
    }
    gridbar(bar, gen);
  }
  // sA = Wh^32, sB = Wh^256

  // ---- linit: l_1[k] = pre[k*32] ----
  for (int ii = g * 256 + tid; ii < 131072; ii += 65536) {
    int m = ii >> 8, c4 = (ii & 255) * 4;
    const u16* src = pre_b + (((m >> 3) << 5) * 8 + (m & 7)) * 1024 + c4;
    *(ushort4*)(lb0 + m * 1024 + c4) = *(const ushort4*)src;
  }
  gridbar(bar, gen);

  // ---- phase 1: 31 steps, 256 tiles (1/WG); XCD-grouped m-tiles ----
  int mt = g & 7, et = g >> 3;
  for (int c = 2; c <= 32; ++c) {
    const u16* in = (c & 1) ? lb1 : lb0;
    u16* out = (c & 1) ? lb0 : lb1;
    gemm_tile<0>(sm, in, wh_b, mt * 64, et * 32, pre_b, nullptr, out, nullptr,
                 (c == 32) ? lC : nullptr, nullptr, c);
    gridbar(bar, gen);
  }

  // ---- gather: lam0[s*8+b] = lC[chunk s*8] ----
  {
    int ii = g * 256 + tid;
    if (ii < 16384) {
      int r = ii >> 8, e4 = (ii & 255) * 4;
      int src = ((r >> 3) << 6) + (r & 7);
      *(float4*)(lam0 + r * 1024 + e4) = *(const float4*)(lC + src * 1024 + e4);
    }
  }
  gridbar(bar, gen);

  // ---- phase 2a: Lambda chain (7 steps, 512 units => 2/WG) ----
  for (int c = 2; c <= 8; ++c) {
    const float* in = (c & 1) ? lam1 : lam0;
    float* out = (c & 1) ? lam0 : lam1;
    for (int i = 0; i < 2; ++i) {
      int u = i * 256 + g;
      matvec_unit(tid, u & 63, u >> 6, in, sA, lC, out, nullptr, c - 1, 0, true);
    }
    gridbar(bar, gen);
  }
  // Lambda_8 in lam1

  // ---- phase 2b: superchunk chain (7 steps, 64 units) ----
  for (int s = 0; s < 7; ++s) {
    if (g < 64)
      matvec_unit(tid, g, 0, bndS + s * 8192, sB, lam1 + s * 8192,
                  bndS + (s + 1) * 8192, bnd_b + (size_t)(s + 1) * 65536, 0, 0, false);
    gridbar(bar, gen);
  }

  // ---- phase 2c: recover intra-super boundaries (7 steps, 512 units) ----
  for (int c = 1; c <= 7; ++c) {
    const float* in = (c == 1) ? bndS : ((c & 1) ? pc1 : pc0);
    float* out = (c & 1) ? pc0 : pc1;
    for (int i = 0; i < 2; ++i) {
      int u = i * 256 + g;
      matvec_unit(tid, u & 63, u >> 6, in, sA, lC, out, bnd_b, c - 1, c, true);
    }
    gridbar(bar, gen);
  }

  // ---- phase 3: 32 steps with fused h_all + h^2*silu epilogue ----
  for (int c = 1; c <= 32; ++c) {
    const u16* in = (c == 1) ? bnd_b : ((c & 1) ? lb1 : lb0);
    u16* out = (c & 1) ? lb0 : lb1;
    gemm_tile<1>(sm, in, wh_b, mt * 64, et * 32, pre_b, nullptr, out, nullptr,
                 hall, out0, c);
    if (c < 32) gridbar(bar, gen);
  }
}

// ---- power iteration + misc helpers -----------------------------------------
__global__ void k_init(const float* __restrict__ u_in, const float* __restrict__ h0,
                       float* __restrict__ u_cur, float* __restrict__ v_acc,
                       float* __restrict__ u_acc, float* __restrict__ hall0,
                       float* __restrict__ bndS, u16* __restrict__ bndb,
                       unsigned* __restrict__ bar)
{
  int i = blockIdx.x * 256 + threadIdx.x;
  if (i == 0) *bar = 0u;
  if (i < 1024) { u_cur[i] = u_in[i]; v_acc[i] = 0.f; u_acc[i] = 0.f; }
  if (i < 8192) { float h = h0[i]; hall0[i] = h; bndS[i] = h; bndb[i] = f2b(h); }
}

__global__ void k_v(const float* __restrict__ W, const float* __restrict__ u_cur,
                    float* __restrict__ v_acc)
{
  int d = blockIdx.x * 256 + threadIdx.x;
  int e0 = blockIdx.y * 64;
  float a = 0.f;
  for (int e = e0; e < e0 + 64; ++e) a += W[e * 1024 + d] * u_cur[e];
  atomicAdd(&v_acc[d], a);
}

__global__ void k_u(const float* __restrict__ W, const float* __restrict__ v_cur,
                    float* __restrict__ u_acc)
{
  int lg = threadIdx.x & 15, ei = threadIdx.x >> 4;
  int e = blockIdx.y * 16 + ei;
  int d0 = blockIdx.x * 512;
  float a = 0.f;
  for (int i = 0; i < 32; ++i) { int d = d0 + lg + 16 * i; a += W[e * 1024 + d] * v_cur[d]; }
#pragma unroll
  for (int m = 1; m < 16; m <<= 1) a += __shfl_xor(a, m);
  if (lg == 0) atomicAdd(&u_acc[e], a);
}

__global__ void k_norm(const float* __restrict__ acc, float* __restrict__ outv,
                       float* __restrict__ z1)
{
  __shared__ float red[16];
  int t = threadIdx.x;
  float x = acc[t];
  float ss = x * x;
#pragma unroll
  for (int m = 1; m < 64; m <<= 1) ss += __shfl_xor(ss, m);
  if ((t & 63) == 0) red[t >> 6] = ss;
  __syncthreads();
  if (t < 64) {
    float s = (t < 16) ? red[t] : 0.f;
#pragma unroll
    for (int m = 1; m < 16; m <<= 1) s += __shfl_xor(s, m);
    if (t == 0) red[0] = s;
  }
  __syncthreads();
  float nrm = sqrtf(red[0]) + 1e-8f;
  outv[t] = x / nrm;
  z1[t] = 0.f;
}

__global__ void k_sigma(const float* __restrict__ acc, float* __restrict__ scale)
{
  __shared__ float red[16];
  int t = threadIdx.x;
  float x = acc[t];
  float ss = x * x;
#pragma unroll
  for (int m = 1; m < 64; m <<= 1) ss += __shfl_xor(ss, m);
  if ((t & 63) == 0) red[t >> 6] = ss;
  __syncthreads();
  if (t < 64) {
    float s = (t < 16) ? red[t] : 0.f;
#pragma unroll
    for (int m = 1; m < 16; m <<= 1) s += __shfl_xor(s, m);
    if (t == 0) {
      float sigma = s / (sqrtf(s) + 1e-8f);
      scale[0] = 0.95f / (sigma + 1e-8f);
    }
  }
}

__global__ void k_scale(const float* __restrict__ W, const float* __restrict__ scale,
                        u16* __restrict__ wb, u16* __restrict__ wbT)
{
  int i = blockIdx.x * 256 + threadIdx.x;
  float v = W[i] * scale[0];
  u16 h = f2b(v);
  wb[i] = h;
  wbT[(i & 1023) * 1024 + (i >> 10)] = h;
}

__global__ void k_cvt(const float* __restrict__ in, u16* __restrict__ out, int n)
{
  int i = (blockIdx.x * 256 + threadIdx.x) * 4;
  if (i >= n) return;
  float4 v = *(const float4*)(in + i);
  ushort4 o;
  o.x = f2b(v.x); o.y = f2b(v.y); o.z = f2b(v.z); o.w = f2b(v.w);
  *(ushort4*)(out + i) = o;
}

extern "C" void kernel_launch(void* const* d_in, const int* in_sizes, int n_in,
                              void* d_out, int out_size, void* d_ws, size_t ws_size,
                              hipStream_t stream)
{
  (void)in_sizes; (void)n_in; (void)out_size; (void)ws_size;
  const float* x  = (const float*)d_in[0];
  const float* h0 = (const float*)d_in[1];
  const float* Wx = (const float*)d_in[2];
  const float* Wh = (const float*)d_in[3];
  const float* bv = (const float*)d_in[4];
  const float* uv = (const float*)d_in[5];

  float* out0 = (float*)d_out;
  float* hall = out0 + 16777216;

  char* ws = (char*)d_ws;
  u16*   wh_b  = (u16*)(ws + 33554432);
  u16*   whT_b = (u16*)(ws + 35651584);
  u16*   wxb   = (u16*)(ws + 48234496);   // aliases lb0/lb1, dead until linit
  u16*   bnd_b = (u16*)(ws + 50331648);
  float* bndS  = (float*)(ws + 51904512);
  float* u_cur = (float*)(ws + 52690944);
  float* v_cur = u_cur + 1024;
  float* v_acc = u_cur + 2048;
  float* u_acc = u_cur + 3072;
  float* scale = u_cur + 4096;
  unsigned* bar = (unsigned*)(ws + 52711424);
  u16*   xb    = (u16*)d_out;             // x bf16 staged in out0 region

  k_init<<<32, 256, 0, stream>>>(uv, h0, u_cur, v_acc, u_acc, hall, bndS, bnd_b, bar);

  for (int it = 0; it < 3; ++it) {
    k_v<<<dim3(4, 16), 256, 0, stream>>>(Wh, u_cur, v_acc);
    k_norm<<<1, 1024, 0, stream>>>(v_acc, v_cur, u_acc);
    k_u<<<dim3(2, 64), 256, 0, stream>>>(Wh, v_cur, u_acc);
    if (it < 2) k_norm<<<1, 1024, 0, stream>>>(u_acc, u_cur, v_acc);
    else        k_sigma<<<1, 1024, 0, stream>>>(u_acc, scale);
  }
  k_scale<<<4096, 256, 0, stream>>>(Wh, scale, wh_b, whT_b);

  k_cvt<<<16384, 256, 0, stream>>>(x, xb, 16777216);
  k_cvt<<<1024, 256, 0, stream>>>(Wx, wxb, 1048576);

  void* kargs[3];
  char* ws_a = ws; const float* bv_a = bv; float* o0_a = out0;
  kargs[0] = &ws_a; kargs[1] = &bv_a; kargs[2] = &o0_a;
  hipLaunchCooperativeKernel((void*)persist, dim3(256), dim3(256), kargs, 0, stream);
}

// Round 5
// 2110.247 us; speedup vs baseline: 1.1842x; 1.1842x over previous
//
#include <hip/hip_runtime.h>
#include <hip/hip_bf16.h>

#define DEV __device__ __forceinline__

typedef __bf16 bf16x8 __attribute__((ext_vector_type(8)));
typedef float  f32x4  __attribute__((ext_vector_type(4)));
typedef unsigned short u16;
typedef unsigned long long u64;

DEV u16   f2b(float f) { __bf16 h = (__bf16)f; return __builtin_bit_cast(u16, h); }
DEV float b2f(u16 x)   { return __builtin_bit_cast(float, ((unsigned)x) << 16); }

// ---- system-scope (L3-coherent) access helpers: per-access bypass, no fences
DEV float ldf(const float* p)  { return __hip_atomic_load(p, __ATOMIC_RELAXED, __HIP_MEMORY_SCOPE_SYSTEM); }
DEV u64   ld64(const void* p)  { return __hip_atomic_load((const u64*)p, __ATOMIC_RELAXED, __HIP_MEMORY_SCOPE_SYSTEM); }
DEV void  stf(float* p, float v){ __hip_atomic_store(p, v, __ATOMIC_RELAXED, __HIP_MEMORY_SCOPE_SYSTEM); }
DEV void  st16(u16* p, u16 v)  { __hip_atomic_store(p, v, __ATOMIC_RELAXED, __HIP_MEMORY_SCOPE_SYSTEM); }
DEV void  st64(void* p, u64 v) { __hip_atomic_store((u64*)p, v, __ATOMIC_RELAXED, __HIP_MEMORY_SCOPE_SYSTEM); }

DEV void gl_lds16(const u16* g, u16* l) {
  __builtin_amdgcn_global_load_lds((const __attribute__((address_space(1))) void*)g,
                                   (__attribute__((address_space(3))) void*)l, 16, 0, 0);
}

// Fence-free grid barrier: __syncthreads drains all stores (vmcnt0 before
// s_barrier), then one relaxed system-scope atomic count + spin. No L2
// writeback/invalidate — data coherence is handled per-access (ldf/ld64/stf).
// Monotonic counter, zeroed by k_init each launch => graph-replay-safe.
DEV void gridbar(unsigned* bar, unsigned& gen) {
  __syncthreads();
  if (threadIdx.x == 0) {
    gen += 256u;   // NWG
    __hip_atomic_fetch_add(bar, 1u, __ATOMIC_RELAXED, __HIP_MEMORY_SCOPE_SYSTEM);
    while (__hip_atomic_load(bar, __ATOMIC_RELAXED, __HIP_MEMORY_SCOPE_SYSTEM) < gen)
      __builtin_amdgcn_s_sleep(2);
  }
  __syncthreads();
}

// ---------------------------------------------------------------------------
// 64x32-tile GEMM step, BK=128 double-buffered. D[m,e] = sum_d A[m,d]*B[e,d].
// LDS: A 2x16KB rows 64x256B, B 2x8KB rows 32x256B, byte ^= (row&7)<<4 swizzle.
// ADEV=false: A staged via global_load_lds (read-only/virgin buffers).
// ADEV=true : A staged via system-scope reg loads (issued one tile early) +
//             ds_write — required for rewritten chain buffers (bypass L1/L2).
// MODE 0: += pre[t(c-1)], chain bf16 out (+lC fp32);  MODE 1: phase3 + epilogue
// MODE 2: squaring (D and D^T, bypass stores);        MODE 3: += bias -> pre_b
// ---------------------------------------------------------------------------
template<int MODE, bool ADEV>
DEV void gemm_tile(u16* sm, const u16* A, const u16* B,
                   int m0, int e0, const u16* preb,
                   const float* bias, u16* outb,
                   u16* outbT, float* outf,
                   float* out0, int c)
{
  const int K = 1024;
  int tid = threadIdx.x, lane = tid & 63, w = tid >> 6;
  int wrow = (w >> 1) << 5, wcol = (w & 1) << 4;
  u16* As = sm;            // [2][8192] u16
  u16* Bs = sm + 16384;    // [2][4096] u16

  f32x4 acc[2] = {};

  // B staging (always gl_lds; wh_b / wxb / power-buffers are never rewritten)
  int rB[2], cB[2];
#pragma unroll
  for (int j = 0; j < 2; ++j) {
    int p = (j * 4 + w) * 1024 + lane * 16;
    int r = p >> 8, o = (p & 255) ^ ((r & 7) << 4);
    rB[j] = r; cB[j] = o >> 1;
  }
  auto stageB = [&](int bufb, int kt) {
#pragma unroll
    for (int j = 0; j < 2; ++j)
      gl_lds16(B + (e0 + rB[j]) * K + kt + cB[j], Bs + bufb * 4096 + (j * 4 + w) * 512);
  };

  // A staging
  int rA[4], cA[4];
  if constexpr (!ADEV) {
#pragma unroll
    for (int j = 0; j < 4; ++j) {
      int p = (j * 4 + w) * 1024 + lane * 16;
      int r = p >> 8, o = (p & 255) ^ ((r & 7) << 4);
      rA[j] = r; cA[j] = o >> 1;
    }
  }
  auto stageA = [&](int bufb, int kt) {
#pragma unroll
    for (int j = 0; j < 4; ++j)
      gl_lds16(A + (m0 + rA[j]) * K + kt + cA[j], As + bufb * 8192 + (j * 4 + w) * 512);
  };

  // ADEV path: thread owns row ar = tid>>2, 16B-slots c16 = (tid&3)*4 + j
  int ar = tid >> 2, ac0 = (tid & 3) * 4;
  u64 va[8];
  auto aload = [&](int kt) {
    const u16* base = A + (size_t)(m0 + ar) * 1024 + kt;
#pragma unroll
    for (int j = 0; j < 4; ++j) {
      const u64* p = (const u64*)(base + (ac0 + j) * 8);
      va[j * 2]     = ld64(p);
      va[j * 2 + 1] = ld64(p + 1);
    }
  };
  auto awrite = [&](int bufb) {
#pragma unroll
    for (int j = 0; j < 4; ++j) {
      int c16 = ac0 + j;
      int off = ar * 256 + ((c16 * 16) ^ ((ar & 7) << 4));
      uint4 v;
      v.x = (unsigned)va[j * 2];     v.y = (unsigned)(va[j * 2] >> 32);
      v.z = (unsigned)va[j * 2 + 1]; v.w = (unsigned)(va[j * 2 + 1] >> 32);
      *(uint4*)((char*)(As + bufb * 8192) + off) = v;
    }
  };

  // prologue
  if constexpr (ADEV) { aload(0); stageB(0, 0); awrite(0); }
  else                { stageA(0, 0); stageB(0, 0); }
  asm volatile("s_waitcnt vmcnt(0)" ::: "memory");
  __syncthreads();

  int buf = 0;
  for (int kt = 0; kt < K; kt += 128, buf ^= 1) {
    bool more = (kt + 128 < K);
    if (more) {
      if constexpr (ADEV) aload(kt + 128);
      else                stageA(buf ^ 1, kt + 128);
      stageB(buf ^ 1, kt + 128);
    }
#pragma unroll
    for (int ks = 0; ks < 4; ++ks) {
      int oa = ks * 64 + ((lane >> 4) << 4);
      int ra0 = wrow + (lane & 15), ra1 = ra0 + 16;
      int rb  = wcol + (lane & 15);
      bf16x8 af0 = *(const bf16x8*)((const char*)(As + buf * 8192) + ra0 * 256 + (oa ^ ((ra0 & 7) << 4)));
      bf16x8 af1 = *(const bf16x8*)((const char*)(As + buf * 8192) + ra1 * 256 + (oa ^ ((ra1 & 7) << 4)));
      bf16x8 bfv = *(const bf16x8*)((const char*)(Bs + buf * 4096) + rb * 256 + (oa ^ ((rb & 7) << 4)));
      acc[0] = __builtin_amdgcn_mfma_f32_16x16x32_bf16(af0, bfv, acc[0], 0, 0, 0);
      acc[1] = __builtin_amdgcn_mfma_f32_16x16x32_bf16(af1, bfv, acc[1], 0, 0, 0);
    }
    if (more) { if constexpr (ADEV) awrite(buf ^ 1); }
    asm volatile("s_waitcnt vmcnt(0)" ::: "memory");
    __syncthreads();
  }

  int l4 = ((lane >> 4) << 2), lc = lane & 15;
#pragma unroll
  for (int s = 0; s < 2; ++s)
#pragma unroll
    for (int j = 0; j < 4; ++j) {
      int row = m0 + wrow + s * 16 + l4 + j;   // C/D: row=(lane>>4)*4+reg
      int col = e0 + wcol + lc;                // C/D: col=lane&15
      float v = acc[s][j];
      if (MODE == 0) {
        int pt = ((row >> 3) << 5) + c - 1;
        v += b2f(preb[(pt * 8 + (row & 7)) * 1024 + col]);   // pre_b: read-only, cached
        st16(outb + row * 1024 + col, f2b(v));               // chain: bypass store
        if (outf) stf(outf + row * 1024 + col, v);           // lC
      } else if (MODE == 1) {
        int pt = ((row >> 3) << 5) + c - 1;
        v += b2f(preb[(pt * 8 + (row & 7)) * 1024 + col]);
        st16(outb + row * 1024 + col, f2b(v));
        int t = pt + 1;
        outf[t * 8192 + (row & 7) * 1024 + col] = v;         // h_all: no in-kernel reader
        float sg = 1.f / (1.f + __expf(-v));
        out0[(t - 1) * 8192 + (row & 7) * 1024 + col] = v * v * sg;
      } else if (MODE == 2) {
        u16 h = f2b(v);
        st16(outb + row * 1024 + col, h);
        if (outbT) st16(outbT + col * 1024 + row, h);
      } else {
        v += bias[col];
        st16(outb + row * 1024 + col, f2b(v));               // pre_b
      }
    }
}

// matvec: hout[r,e] = sum_d W[e,d]*hin[r,d] + addv[map(r),e]
// hin/addv are rewritten chain buffers -> bypass loads; W is a never-rewritten
// power buffer -> normal cached loads.
DEV void matvec_unit(int tid, int e16, int rblk, const float* hin,
                     const u16* W, const float* addv,
                     float* hout, u16* houtb,
                     int acoff, int bcoff, bool nr64)
{
  int lg = tid & 15;
  int e = e16 * 16 + (tid >> 4);
  int r0 = rblk * 8;
  float acc[8] = {0,0,0,0,0,0,0,0};
  const u16* wrow = W + e * 1024;
#pragma unroll
  for (int i = 0; i < 8; ++i) {
    int d0 = lg * 8 + i * 128;
    ushort4 w0 = *(const ushort4*)(wrow + d0);
    ushort4 w1 = *(const ushort4*)(wrow + d0 + 4);
    float wa = b2f(w0.x), wb = b2f(w0.y), wc = b2f(w0.z), wd = b2f(w0.w);
    float we_ = b2f(w1.x), wf = b2f(w1.y), wg = b2f(w1.z), wh = b2f(w1.w);
#pragma unroll
    for (int b = 0; b < 8; ++b) {
      const float* hr = hin + (r0 + b) * 1024 + d0;
      u64 q0 = ld64(hr), q1 = ld64(hr + 2), q2 = ld64(hr + 4), q3 = ld64(hr + 6);
      float2 f0 = __builtin_bit_cast(float2, q0), f1 = __builtin_bit_cast(float2, q1);
      float2 f2 = __builtin_bit_cast(float2, q2), f3 = __builtin_bit_cast(float2, q3);
      acc[b] += wa*f0.x + wb*f0.y + wc*f1.x + wd*f1.y
              + we_*f2.x + wf*f2.y + wg*f3.x + wh*f3.y;
    }
  }
#pragma unroll
  for (int m = 1; m < 16; m <<= 1)
#pragma unroll
    for (int b = 0; b < 8; ++b) acc[b] += __shfl_xor(acc[b], m);
  if (lg == 0) {
#pragma unroll
    for (int b = 0; b < 8; ++b) {
      int r = r0 + b;
      int ai = nr64 ? (((r >> 3) << 6) + (acoff << 3) + (r & 7)) : r;
      float v = acc[b] + ldf(addv + ai * 1024 + e);
      stf(hout + r * 1024 + e, v);
      if (houtb) {
        int bi = nr64 ? (((r >> 3) << 6) + (bcoff << 3) + (r & 7)) : r;
        st16(houtb + bi * 1024 + e, f2b(v));
      }
    }
  }
}

// ---------------------------------------------------------------------------
// Persistent kernel: pre-GEMM, 8 squarings (distinct buffers), phase1, phase2,
// phase3. 256 WGs x 256 threads, fence-free grid barriers.
// ---------------------------------------------------------------------------
__global__ __launch_bounds__(256) void persist(char* __restrict__ ws,
                                               const float* __restrict__ bias,
                                               float* out0)
{
  u16*   pre_b = (u16*)(ws);
  u16*   wh_b  = (u16*)(ws + 33554432);
  u16*   whT_b = (u16*)(ws + 35651584);
  float* lC    = (float*)(ws + 46137344);
  u16*   lb0   = (u16*)(ws + 48234496);
  u16*   lb1   = (u16*)(ws + 49283072);
  u16*   wxb   = (u16*)(ws + 48234496);   // aliases lb0/lb1 (dead until linit)
  u16*   bnd_b = (u16*)(ws + 50331648);
  float* lam0  = (float*)(ws + 51380224);
  float* lam1  = (float*)(ws + 51642368);
  float* bndS  = (float*)(ws + 51904512);
  float* pc0   = (float*)(ws + 52166656);
  float* pc1   = (float*)(ws + 52428800);
  unsigned* bar = (unsigned*)(ws + 52711424);

  float* hall = out0 + 16777216;
  u16*   xb   = (u16*)out0;               // x bf16 staged in out0 region

  // Wh power buffers: 15 distinct 2MB regions in the hall area (dead until
  // phase 3) so no buffer is ever rewritten -> normal cached reads are safe.
  char* hb = (char*)hall;
  const size_t MB2 = 2097152;
  u16* pw[15];
#pragma unroll
  for (int i = 0; i < 15; ++i) pw[i] = (u16*)(hb + 20971520 + i * MB2);
  // pw: 0=p2 1=p2T 2=p4 3=p4T 4=p8 5=p8T 6=p16 7=p16T 8=p32 9=p32T
  //     10=p64 11=p64T 12=p128 13=p128T 14=p256
  u16* W32  = pw[8];
  u16* W256 = pw[14];

  __shared__ u16 sm[24576];   // 48KB: A dbuf 32KB + B dbuf 16KB
  int g = blockIdx.x, tid = threadIdx.x;
  unsigned gen = 0;

  // ---- step 0: pre = x @ Wx^T + b  (8192 tiles, 32 per WG) ----
  for (int i = 0; i < 32; ++i) {
    int t = i * 256 + g;
    gemm_tile<3, false>(sm, xb, wxb, (t >> 5) * 64, (t & 31) * 32, nullptr, bias,
                        pre_b, nullptr, nullptr, nullptr, 0);
  }
  gridbar(bar, gen);

  // ---- Wh powers by squaring: 8 steps, distinct buffers, 512 tiles (2/WG) --
  const u16* qa[8]  = {wh_b,  pw[0], pw[2], pw[4], pw[6], pw[8],  pw[10], pw[12]};
  const u16* qat[8] = {whT_b, pw[1], pw[3], pw[5], pw[7], pw[9],  pw[11], pw[13]};
  u16*       qo[8]  = {pw[0], pw[2], pw[4], pw[6], pw[8], pw[10], pw[12], pw[14]};
  u16*       qot[8] = {pw[1], pw[3], pw[5], pw[7], pw[9], pw[11], pw[13], nullptr};
  for (int sq = 0; sq < 8; ++sq) {
    for (int i = 0; i < 2; ++i) {
      int t = i * 256 + g;
      gemm_tile<2, false>(sm, qa[sq], qat[sq], (t >> 5) * 64, (t & 31) * 32, nullptr,
                          nullptr, qo[sq], qot[sq], nullptr, nullptr, 0);
    }
    gridbar(bar, gen);
  }

  // ---- linit: l_1[k] = pre[k*32] ----
  for (int ii = g * 256 + tid; ii < 131072; ii += 65536) {
    int m = ii >> 8, c4 = (ii & 255) * 4;
    const u64* src = (const u64*)(pre_b + (((m >> 3) << 5) * 8 + (m & 7)) * 1024 + c4);
    st64(lb0 + m * 1024 + c4, *src);
  }
  gridbar(bar, gen);

  // ---- phase 1: 31 steps, 256 tiles (1/WG) ----
  int mt = g & 7, et = g >> 3;
  for (int c = 2; c <= 32; ++c) {
    const u16* in = (c & 1) ? lb1 : lb0;
    u16* out = (c & 1) ? lb0 : lb1;
    gemm_tile<0, true>(sm, in, wh_b, mt * 64, et * 32, pre_b, nullptr, out, nullptr,
                       (c == 32) ? lC : nullptr, nullptr, c);
    gridbar(bar, gen);
  }

  // ---- gather: lam0[s*8+b] = lC[chunk s*8] (lC read-only from here on) ----
  {
    int ii = g * 256 + tid;
    if (ii < 16384) {
      int r = ii >> 8, e4 = (ii & 255) * 4;
      int src = ((r >> 3) << 6) + (r & 7);
      const u64* sp = (const u64*)(lC + src * 1024 + e4);
      st64(lam0 + r * 1024 + e4, sp[0]);
      st64(lam0 + r * 1024 + e4 + 2, sp[1]);
    }
  }
  gridbar(bar, gen);

  // ---- phase 2a: Lambda chain (7 steps, 512 units => 2/WG, W = Wh^32) ----
  for (int c = 2; c <= 8; ++c) {
    const float* in = (c & 1) ? lam1 : lam0;
    float* out = (c & 1) ? lam0 : lam1;
    for (int i = 0; i < 2; ++i) {
      int u = i * 256 + g;
      matvec_unit(tid, u & 63, u >> 6, in, W32, lC, out, nullptr, c - 1, 0, true);
    }
    gridbar(bar, gen);
  }
  // Lambda_8 in lam1

  // ---- phase 2b: superchunk chain (7 steps, 64 units, W = Wh^256) ----
  for (int s = 0; s < 7; ++s) {
    if (g < 64)
      matvec_unit(tid, g, 0, bndS + s * 8192, W256, lam1 + s * 8192,
                  bndS + (s + 1) * 8192, bnd_b + (size_t)(s + 1) * 65536, 0, 0, false);
    gridbar(bar, gen);
  }

  // ---- phase 2c: recover intra-super boundaries (7 steps, 512 units) ----
  for (int c = 1; c <= 7; ++c) {
    const float* in = (c == 1) ? bndS : ((c & 1) ? pc1 : pc0);
    float* out = (c & 1) ? pc0 : pc1;
    for (int i = 0; i < 2; ++i) {
      int u = i * 256 + g;
      matvec_unit(tid, u & 63, u >> 6, in, W32, lC, out, bnd_b, c - 1, c, true);
    }
    gridbar(bar, gen);
  }

  // ---- phase 3: 32 steps with fused h_all + h^2*silu epilogue ----
  for (int c = 1; c <= 32; ++c) {
    const u16* in = (c == 1) ? bnd_b : ((c & 1) ? lb1 : lb0);
    u16* out = (c & 1) ? lb0 : lb1;
    gemm_tile<1, true>(sm, in, wh_b, mt * 64, et * 32, pre_b, nullptr, out, nullptr,
                       hall, out0, c);
    if (c < 32) gridbar(bar, gen);
  }
}

// ---- power iteration + misc helpers -----------------------------------------
__global__ void k_init(const float* __restrict__ u_in, const float* __restrict__ h0,
                       float* __restrict__ u_cur, float* __restrict__ v_acc,
                       float* __restrict__ u_acc, float* __restrict__ hall0,
                       float* __restrict__ bndS, u16* __restrict__ bndb,
                       unsigned* __restrict__ bar)
{
  int i = blockIdx.x * 256 + threadIdx.x;
  if (i == 0) *bar = 0u;
  if (i < 1024) { u_cur[i] = u_in[i]; v_acc[i] = 0.f; u_acc[i] = 0.f; }
  if (i < 8192) { float h = h0[i]; hall0[i] = h; bndS[i] = h; bndb[i] = f2b(h); }
}

__global__ void k_v(const float* __restrict__ W, const float* __restrict__ u_cur,
                    float* __restrict__ v_acc)
{
  int d = blockIdx.x * 256 + threadIdx.x;
  int e0 = blockIdx.y * 64;
  float a = 0.f;
  for (int e = e0; e < e0 + 64; ++e) a += W[e * 1024 + d] * u_cur[e];
  atomicAdd(&v_acc[d], a);
}

__global__ void k_u(const float* __restrict__ W, const float* __restrict__ v_cur,
                    float* __restrict__ u_acc)
{
  int lg = threadIdx.x & 15, ei = threadIdx.x >> 4;
  int e = blockIdx.y * 16 + ei;
  int d0 = blockIdx.x * 512;
  float a = 0.f;
  for (int i = 0; i < 32; ++i) { int d = d0 + lg + 16 * i; a += W[e * 1024 + d] * v_cur[d]; }
#pragma unroll
  for (int m = 1; m < 16; m <<= 1) a += __shfl_xor(a, m);
  if (lg == 0) atomicAdd(&u_acc[e], a);
}

__global__ void k_norm(const float* __restrict__ acc, float* __restrict__ outv,
                       float* __restrict__ z1)
{
  __shared__ float red[16];
  int t = threadIdx.x;
  float x = acc[t];
  float ss = x * x;
#pragma unroll
  for (int m = 1; m < 64; m <<= 1) ss += __shfl_xor(ss, m);
  if ((t & 63) == 0) red[t >> 6] = ss;
  __syncthreads();
  if (t < 64) {
    float s = (t < 16) ? red[t] : 0.f;
#pragma unroll
    for (int m = 1; m < 16; m <<= 1) s += __shfl_xor(s, m);
    if (t == 0) red[0] = s;
  }
  __syncthreads();
  float nrm = sqrtf(red[0]) + 1e-8f;
  outv[t] = x / nrm;
  z1[t] = 0.f;
}

__global__ void k_sigma(const float* __restrict__ acc, float* __restrict__ scale)
{
  __shared__ float red[16];
  int t = threadIdx.x;
  float x = acc[t];
  float ss = x * x;
#pragma unroll
  for (int m = 1; m < 64; m <<= 1) ss += __shfl_xor(ss, m);
  if ((t & 63) == 0) red[t >> 6] = ss;
  __syncthreads();
  if (t < 64) {
    float s = (t < 16) ? red[t] : 0.f;
#pragma unroll
    for (int m = 1; m < 16; m <<= 1) s += __shfl_xor(s, m);
    if (t == 0) {
      float sigma = s / (sqrtf(s) + 1e-8f);
      scale[0] = 0.95f / (sigma + 1e-8f);
    }
  }
}

__global__ void k_scale(const float* __restrict__ W, const float* __restrict__ scale,
                        u16* __restrict__ wb, u16* __restrict__ wbT)
{
  int i = blockIdx.x * 256 + threadIdx.x;
  float v = W[i] * scale[0];
  u16 h = f2b(v);
  wb[i] = h;
  wbT[(i & 1023) * 1024 + (i >> 10)] = h;
}

__global__ void k_cvt(const float* __restrict__ in, u16* __restrict__ out, int n)
{
  int i = (blockIdx.x * 256 + threadIdx.x) * 4;
  if (i >= n) return;
  float4 v = *(const float4*)(in + i);
  ushort4 o;
  o.x = f2b(v.x); o.y = f2b(v.y); o.z = f2b(v.z); o.w = f2b(v.w);
  *(ushort4*)(out + i) = o;
}

extern "C" void kernel_launch(void* const* d_in, const int* in_sizes, int n_in,
                              void* d_out, int out_size, void* d_ws, size_t ws_size,
                              hipStream_t stream)
{
  (void)in_sizes; (void)n_in; (void)out_size; (void)ws_size;
  const float* x  = (const float*)d_in[0];
  const float* h0 = (const float*)d_in[1];
  const float* Wx = (const float*)d_in[2];
  const float* Wh = (const float*)d_in[3];
  const float* bv = (const float*)d_in[4];
  const float* uv = (const float*)d_in[5];

  float* out0 = (float*)d_out;
  float* hall = out0 + 16777216;

  char* ws = (char*)d_ws;
  u16*   wh_b  = (u16*)(ws + 33554432);
  u16*   whT_b = (u16*)(ws + 35651584);
  u16*   wxb   = (u16*)(ws + 48234496);   // aliases lb0/lb1, dead until linit
  u16*   bnd_b = (u16*)(ws + 50331648);
  float* bndS  = (float*)(ws + 51904512);
  float* u_cur = (float*)(ws + 52690944);
  float* v_cur = u_cur + 1024;
  float* v_acc = u_cur + 2048;
  float* u_acc = u_cur + 3072;
  float* scale = u_cur + 4096;
  unsigned* bar = (unsigned*)(ws + 52711424);
  u16*   xb    = (u16*)d_out;             // x bf16 staged in out0 region

  k_init<<<32, 256, 0, stream>>>(uv, h0, u_cur, v_acc, u_acc, hall, bndS, bnd_b, bar);

  for (int it = 0; it < 3; ++it) {
    k_v<<<dim3(4, 16), 256, 0, stream>>>(Wh, u_cur, v_acc);
    k_norm<<<1, 1024, 0, stream>>>(v_acc, v_cur, u_acc);
    k_u<<<dim3(2, 64), 256, 0, stream>>>(Wh, v_cur, u_acc);
    if (it < 2) k_norm<<<1, 1024, 0, stream>>>(u_acc, u_cur, v_acc);
    else        k_sigma<<<1, 1024, 0, stream>>>(u_acc, scale);
  }
  k_scale<<<4096, 256, 0, stream>>>(Wh, scale, wh_b, whT_b);

  k_cvt<<<16384, 256, 0, stream>>>(x, xb, 16777216);
  k_cvt<<<1024, 256, 0, stream>>>(Wx, wxb, 1048576);

  void* kargs[3];
  char* ws_a = ws; const float* bv_a = bv; float* o0_a = out0;
  kargs[0] = &ws_a; kargs[1] = &bv_a; kargs[2] = &o0_a;
  hipLaunchCooperativeKernel((void*)persist, dim3(256), dim3(256), kargs, 0, stream);
}